// Round 11
// baseline (776.061 us; speedup 1.0000x reference)
//
#include <hip/hip_runtime.h>
#include <hip/hip_bf16.h>

#define N_NODES   100000
#define N_EDGES   1600000
#define N_GRAPHS  64
#define FDIM      128
#define N_LABELS  20
#define NBK       64                  // nodes per dst-bucket
#define P_BKT     1563                // ceil(N_NODES/NBK)
#define NCHUNKS   64                  // edge chunks
#define CHUNK     25000               // N_EDGES / NCHUNKS
#define SCAN_M    (P_BKT * NCHUNKS)   // 100032
#define SB_BLOCKS 391                 // ceil(SCAN_M/256); also covers N_NODES

__device__ __forceinline__ unsigned bfr(float v) {   // fp32 -> bf16 (RTNE-ish)
  unsigned b = __float_as_uint(v);
  return (b + 0x7fffu + ((b >> 16) & 1u)) >> 16;
}

// ---------------- init: zero pool/zrow, csr pads, offsets[N] ----------------
__global__ __launch_bounds__(256) void init_kernel(
    float* __restrict__ pool, float* __restrict__ zrow,
    int* __restrict__ csr, int* __restrict__ csr2, int* __restrict__ offsets) {
  int i = blockIdx.x * 256 + threadIdx.x;
  if (i < N_GRAPHS * 256) pool[i] = 0.f;
  if (i < FDIM) zrow[i] = 0.f;
  if (i < 8) { csr[N_EDGES + i] = 0; csr2[N_EDGES + i] = 0; }
  if (i == 8) offsets[N_NODES] = N_EDGES;
}

// ---------------- emb -> bf16 (12.8 MB) ----------------
__global__ __launch_bounds__(256) void cvt_emb_kernel(
    const float* __restrict__ emb, unsigned short* __restrict__ embbf) {
  int i = blockIdx.x * 256 + threadIdx.x;   // quad id, 1,600,000 total
  float4 v = ((const float4*)emb)[i];
  uint2 o;
  o.x = bfr(v.x) | (bfr(v.y) << 16);
  o.y = bfr(v.z) | (bfr(v.w) << 16);
  ((uint2*)embbf)[i] = o;
}

// ---------------- A1: per-chunk bucket histogram ----------------
__global__ __launch_bounds__(256) void histA_kernel(
    const int* __restrict__ ei, int* __restrict__ cntmat) {
  __shared__ int hist[P_BKT];
  int tid = threadIdx.x;
  for (int i = tid; i < P_BKT; i += 256) hist[i] = 0;
  __syncthreads();
  int base = blockIdx.x * CHUNK;
  for (int i = tid; i < CHUNK; i += 256) {
    int d = ei[N_EDGES + base + i];
    atomicAdd(&hist[d >> 6], 1);
  }
  __syncthreads();
  for (int p = tid; p < P_BKT; p += 256)
    cntmat[p * NCHUNKS + blockIdx.x] = hist[p];
}

// ---------------- A2: 3-level exclusive scan over cntmat (bucket-major) -----
__global__ __launch_bounds__(256) void scanB1_kernel(
    const int* __restrict__ v, int* __restrict__ part,
    int* __restrict__ bsum) {
  __shared__ int s[256];
  int tid = threadIdx.x;
  int i = blockIdx.x * 256 + tid;
  int val = (i < SCAN_M) ? v[i] : 0;
  s[tid] = val;
  __syncthreads();
  for (int off = 1; off < 256; off <<= 1) {
    int t = (tid >= off) ? s[tid - off] : 0;
    __syncthreads();
    s[tid] += t;
    __syncthreads();
  }
  if (i < SCAN_M) part[i] = s[tid] - val;
  if (tid == 255) bsum[blockIdx.x] = s[255];
}

__global__ __launch_bounds__(512) void scanB2_kernel(int* __restrict__ bsum) {
  __shared__ int s[512];
  int tid = threadIdx.x;
  int v = (tid < SB_BLOCKS) ? bsum[tid] : 0;
  s[tid] = v;
  __syncthreads();
  for (int off = 1; off < 512; off <<= 1) {
    int t = (tid >= off) ? s[tid - off] : 0;
    __syncthreads();
    s[tid] += t;
    __syncthreads();
  }
  if (tid < SB_BLOCKS) bsum[tid] = s[tid] - v;
}

__global__ __launch_bounds__(256) void scanB3_kernel(
    int* __restrict__ part, const int* __restrict__ bsum,
    int* __restrict__ bstart) {
  int i = blockIdx.x * 256 + threadIdx.x;
  if (i < SCAN_M) {
    int o = part[i] + bsum[blockIdx.x];
    part[i] = o;
    if ((i & (NCHUNKS - 1)) == 0) bstart[i >> 6] = o;
  }
  if (blockIdx.x == 0 && threadIdx.x == 0) bstart[P_BKT] = N_EDGES;
}

// ---------------- A3: scatter edges grouped by bucket (packed src<<6|ldst) --
__global__ __launch_bounds__(256) void scatA_kernel(
    const int* __restrict__ ei, const int* __restrict__ S,
    int* __restrict__ ebuf) {
  __shared__ int rc[P_BKT];
  int tid = threadIdx.x;
  for (int p = tid; p < P_BKT; p += 256)
    rc[p] = S[p * NCHUNKS + blockIdx.x];
  __syncthreads();
  int base = blockIdx.x * CHUNK;
  for (int i = tid; i < CHUNK; i += 256) {
    int s0 = ei[base + i];
    int d0 = ei[N_EDGES + base + i];
    int pos = atomicAdd(&rc[d0 >> 6], 1);
    ebuf[pos] = (s0 << 6) | (d0 & 63);
  }
}

// ---------------- A4: per-bucket CSR build (single-writer csr window) -------
__global__ __launch_bounds__(256) void fill2_kernel(
    const int* __restrict__ ebuf, const int* __restrict__ bstart,
    const int* __restrict__ x, int* __restrict__ offsets,
    int* __restrict__ csr, int* __restrict__ csr2) {
  __shared__ int ldeg[NBK], loffs[NBK], rc2[NBK];
  int tid = threadIdx.x;
  int p = blockIdx.x;
  int beg = bstart[p], end = bstart[p + 1];
  if (tid < NBK) ldeg[tid] = 0;
  __syncthreads();
  for (int i = beg + tid; i < end; i += 256)
    atomicAdd(&ldeg[ebuf[i] & 63], 1);
  __syncthreads();
  if (tid == 0) {
    int run = 0;
    for (int r = 0; r < NBK; ++r) { loffs[r] = run; run += ldeg[r]; }
  }
  __syncthreads();
  if (tid < NBK) {
    rc2[tid] = loffs[tid];
    int gn = p * NBK + tid;
    if (gn < N_NODES) offsets[gn] = beg + loffs[tid];
  }
  __syncthreads();
  for (int i = beg + tid; i < end; i += 256) {
    int e = ebuf[i];
    int ld = e & 63;
    int src = e >> 6;
    int pos = atomicAdd(&rc2[ld], 1);
    csr[beg + pos] = src;
    csr2[beg + pos] = x[src];
  }
}

// ---------------- aggregation: agg[i,:] = sum_{j->i} feat[srcidx[j],:] ------
// BF16=true: feat is bf16 rows (256 B), lane reads uint2, converts, fp32 acc.
template <bool BF16>
__global__ __launch_bounds__(256) void agg_kernel(
    const void* __restrict__ feat, const int* __restrict__ srcidx,
    const int* __restrict__ offs, const float* __restrict__ zrow,
    float* __restrict__ aggout) {
  int sub = threadIdx.x >> 5;
  int fq  = threadIdx.x & 31;
  int node = blockIdx.x * 8 + sub;

  float4 acc0 = make_float4(0.f, 0.f, 0.f, 0.f);
  float4 acc1 = make_float4(0.f, 0.f, 0.f, 0.f);
  int s = offs[node], e = offs[node + 1];

  if constexpr (BF16) {
    const uint2* __restrict__ fb = (const uint2*)feat;
    const uint2* __restrict__ zb = (const uint2*)zrow;  // 256 B of zero bits
    for (int p = s; p < e; p += 8) {
      const uint2* rp[8];
#pragma unroll
      for (int u = 0; u < 8; ++u) {
        int iu = srcidx[p + u];                       // safe: padded by 8
        rp[u] = (p + u < e) ? (fb + (size_t)iu * 32) : zb;
      }
      uint2 w[8];
#pragma unroll
      for (int u = 0; u < 8; ++u) w[u] = rp[u][fq];
#pragma unroll
      for (int u = 0; u < 8; ++u) {
        float4& A = (u & 1) ? acc1 : acc0;
        A.x += __uint_as_float(w[u].x << 16);
        A.y += __uint_as_float(w[u].x & 0xffff0000u);
        A.z += __uint_as_float(w[u].y << 16);
        A.w += __uint_as_float(w[u].y & 0xffff0000u);
      }
    }
  } else {
    const float4* __restrict__ f4 = (const float4*)feat;
    const float4* __restrict__ z4 = (const float4*)zrow;
    for (int p = s; p < e; p += 8) {
      const float4* rp[8];
#pragma unroll
      for (int u = 0; u < 8; ++u) {
        int iu = srcidx[p + u];
        rp[u] = (p + u < e) ? (f4 + (size_t)iu * 32) : z4;
      }
      float4 v[8];
#pragma unroll
      for (int u = 0; u < 8; ++u) v[u] = rp[u][fq];
#pragma unroll
      for (int u = 0; u < 8; ++u) {
        float4& A = (u & 1) ? acc1 : acc0;
        A.x += v[u].x; A.y += v[u].y; A.z += v[u].z; A.w += v[u].w;
      }
    }
  }
  float4 a = make_float4(acc0.x + acc1.x, acc0.y + acc1.y,
                         acc0.z + acc1.z, acc0.w + acc1.w);
  ((float4*)aggout)[(size_t)node * 32 + fq] = a;
}

// ---------------- GEMM: hout = relu([agg | h] @ [wrel; wroot] + b) ----------
// R6-proven core + R11 software pipeline: tile t+1's 8 global float4s are
// prefetched into registers right after tile t's LDS-ready barrier, so their
// vmcnt wait lands after the k-loop (hides the random emb[x[n]] row latency).
__global__ __launch_bounds__(256) void gemm_kernel(
    const float* __restrict__ agg, const float* __restrict__ hsrc,
    const int* __restrict__ hidx,
    const float* __restrict__ wrel, const float* __restrict__ wroot,
    const float* __restrict__ bias, float* __restrict__ hout,
    unsigned short* __restrict__ hbf) {
  __shared__ float A_s[128 * 32];
  __shared__ float W_s[32 * 128];
  int tid = threadIdx.x;
  int nodeBase = blockIdx.x * 128;
  int tc = tid & 15, tr = tid >> 4;

  int a_gn[4], a_hr[4], a_q[4], a_lds[4];
#pragma unroll
  for (int i = 0; i < 4; ++i) {
    int f = tid + 256 * i;
    int n = f >> 3, q = f & 7;
    int gn = nodeBase + n;
    if (gn > N_NODES - 1) gn = N_NODES - 1;
    a_gn[i] = gn;
    a_hr[i] = hidx ? hidx[gn] : gn;
    a_q[i] = q;
    a_lds[i] = n * 32 + ((q * 4) ^ (4 * ((n >> 3) & 7)));
  }
  int wk[4], wq[4];
#pragma unroll
  for (int i = 0; i < 4; ++i) {
    int f = tid + 256 * i;
    wk[i] = f >> 5;
    wq[i] = f & 31;
  }

  float acc[8][8];
  {
    float4 b0 = *(const float4*)&bias[4 * tc];
    float4 b1 = *(const float4*)&bias[64 + 4 * tc];
#pragma unroll
    for (int i = 0; i < 8; ++i) {
      acc[i][0] = b0.x; acc[i][1] = b0.y; acc[i][2] = b0.z; acc[i][3] = b0.w;
      acc[i][4] = b1.x; acc[i][5] = b1.y; acc[i][6] = b1.z; acc[i][7] = b1.w;
    }
  }

  const int kx_base = 4 * (tr & 7);

  // prefetch tile 0
  float4 pa[4], pw[4];
#pragma unroll
  for (int i = 0; i < 4; ++i) {
    pa[i] = *(const float4*)(agg + (size_t)a_gn[i] * FDIM + a_q[i] * 4);
    pw[i] = *(const float4*)(wrel + (size_t)wk[i] * FDIM + wq[i] * 4);
  }

#pragma unroll 1
  for (int t = 0; t < 8; ++t) {
    __syncthreads();
#pragma unroll
    for (int i = 0; i < 4; ++i) {
      *(float4*)&A_s[a_lds[i]] = pa[i];
      *(float4*)&W_s[wk[i] * 128 + wq[i] * 4] = pw[i];
    }
    __syncthreads();
    if (t < 7) {
      int tn = t + 1;
#pragma unroll
      for (int i = 0; i < 4; ++i) {
        const float* srcA = (tn < 4)
            ? (agg  + (size_t)a_gn[i] * FDIM + tn * 32 + a_q[i] * 4)
            : (hsrc + (size_t)a_hr[i] * FDIM + (tn - 4) * 32 + a_q[i] * 4);
        pa[i] = *(const float4*)srcA;
        const float* W = (tn < 4) ? (wrel + (size_t)(tn * 32) * FDIM)
                                  : (wroot + (size_t)((tn - 4) * 32) * FDIM);
        pw[i] = *(const float4*)(W + (size_t)wk[i] * FDIM + wq[i] * 4);
      }
    }

#pragma unroll 1
    for (int k0 = 0; k0 < 32; k0 += 4) {
      float4 a4[8];
      int kx = k0 ^ kx_base;
#pragma unroll
      for (int i = 0; i < 8; ++i)
        a4[i] = *(const float4*)&A_s[(8 * tr + i) * 32 + kx];
#pragma unroll
      for (int kk = 0; kk < 4; ++kk) {
        float4 w0 = *(const float4*)&W_s[(k0 + kk) * 128 + 4 * tc];
        float4 w1 = *(const float4*)&W_s[(k0 + kk) * 128 + 64 + 4 * tc];
#pragma unroll
        for (int i = 0; i < 8; ++i) {
          float a = (kk == 0) ? a4[i].x : (kk == 1) ? a4[i].y
                  : (kk == 2) ? a4[i].z : a4[i].w;
          acc[i][0] += a * w0.x; acc[i][1] += a * w0.y;
          acc[i][2] += a * w0.z; acc[i][3] += a * w0.w;
          acc[i][4] += a * w1.x; acc[i][5] += a * w1.y;
          acc[i][6] += a * w1.z; acc[i][7] += a * w1.w;
        }
      }
    }
  }

#pragma unroll
  for (int i = 0; i < 8; ++i) {
    int n = nodeBase + tr * 8 + i;
    if (n < N_NODES) {
      float* o = hout + (size_t)n * FDIM;
      float4 v0, v1;
      v0.x = fmaxf(acc[i][0], 0.f); v0.y = fmaxf(acc[i][1], 0.f);
      v0.z = fmaxf(acc[i][2], 0.f); v0.w = fmaxf(acc[i][3], 0.f);
      v1.x = fmaxf(acc[i][4], 0.f); v1.y = fmaxf(acc[i][5], 0.f);
      v1.z = fmaxf(acc[i][6], 0.f); v1.w = fmaxf(acc[i][7], 0.f);
      *(float4*)(o + 4 * tc) = v0;
      *(float4*)(o + 64 + 4 * tc) = v1;
      if (hbf) {
        unsigned short* ob = hbf + (size_t)n * FDIM;
        uint2 p0, p1;
        p0.x = bfr(v0.x) | (bfr(v0.y) << 16);
        p0.y = bfr(v0.z) | (bfr(v0.w) << 16);
        p1.x = bfr(v1.x) | (bfr(v1.y) << 16);
        p1.y = bfr(v1.z) | (bfr(v1.w) << 16);
        *(uint2*)(ob + 4 * tc) = p0;
        *(uint2*)(ob + 64 + 4 * tc) = p1;
      }
    }
  }
}

// ---------------- per-graph segment boundaries (batch is sorted) ------------
__global__ void find_starts_kernel(const int* __restrict__ batch,
                                   int* __restrict__ start) {
  int i = blockIdx.x * 256 + threadIdx.x;
  if (i >= N_NODES) return;
  int b  = batch[i];
  int bp = (i == 0) ? -1 : batch[i - 1];
  for (int g = bp + 1; g <= b; ++g) start[g] = i;
  if (i == N_NODES - 1) {
    for (int g = b + 1; g <= N_GRAPHS; ++g) start[g] = N_NODES;
  }
}

// ---------------- pooling: max & sum per graph ----------------
__global__ __launch_bounds__(128) void pool_kernel(
    const float* __restrict__ h2, const int* __restrict__ start,
    float* __restrict__ pool) {
  int g = blockIdx.x >> 3;
  int c = blockIdx.x & 7;
  int f = threadIdx.x;
  int s = start[g], e = start[g + 1];
  int len = e - s;
  int lo = s + (int)(((long long)len * c) >> 3);
  int hi = s + (int)(((long long)len * (c + 1)) >> 3);
  float mx = 0.f, sm = 0.f;
  for (int n = lo; n < hi; ++n) {
    float v = h2[(size_t)n * FDIM + f];
    mx = fmaxf(mx, v);
    sm += v;
  }
  atomicMax((unsigned int*)&pool[g * 256 + f], __float_as_uint(mx));
  atomicAdd(&pool[g * 256 + 128 + f], sm);
}

__global__ void pool_fin_kernel(float* __restrict__ pool,
                                const int* __restrict__ start) {
  int gid = blockIdx.x * 256 + threadIdx.x;   // 8192
  int g = gid >> 7, f = gid & 127;
  int cnt = start[g + 1] - start[g];
  float c = (float)(cnt > 1 ? cnt : 1);
  pool[g * 256 + 128 + f] /= c;
}

// ---------------- MLP head ----------------
__global__ void head1_kernel(const float* __restrict__ pool,
                             const float* __restrict__ lw1,
                             const float* __restrict__ lb1,
                             float* __restrict__ t1) {
  int gid = blockIdx.x * 256 + threadIdx.x;   // 8192
  int r = gid >> 7, c = gid & 127;
  float acc = lb1[c];
  for (int k = 0; k < 256; ++k) acc += pool[r * 256 + k] * lw1[k * 128 + c];
  t1[gid] = fmaxf(acc, 0.f);
}

__global__ void head2_kernel(const float* __restrict__ t1,
                             const float* __restrict__ lw2,
                             const float* __restrict__ lb2,
                             float* __restrict__ t2) {
  int gid = blockIdx.x * 256 + threadIdx.x;   // 4096
  int r = gid >> 6, c = gid & 63;
  float acc = lb2[c];
  for (int k = 0; k < 128; ++k) acc += t1[r * 128 + k] * lw2[k * 64 + c];
  t2[gid] = fmaxf(acc, 0.f);
}

__global__ __launch_bounds__(256) void head3_kernel(
    const float* __restrict__ t2, const float* __restrict__ lw3,
    const float* __restrict__ lb3, float* __restrict__ out) {
  __shared__ float lg[N_GRAPHS * N_LABELS];
  __shared__ float col[N_LABELS];
  int tid = threadIdx.x;
  for (int o = tid; o < N_GRAPHS * N_LABELS; o += 256) {
    int r = o / N_LABELS, c = o - r * N_LABELS;
    float acc = lb3[c];
    for (int k = 0; k < 64; ++k) acc += t2[r * 64 + k] * lw3[k * N_LABELS + c];
    lg[o] = acc;
  }
  __syncthreads();
  if (tid < N_LABELS) {
    float m = -1e30f;
    for (int r = 0; r < N_GRAPHS; ++r) m = fmaxf(m, lg[r * N_LABELS + tid]);
    float s = 0.f;
    for (int r = 0; r < N_GRAPHS; ++r) s += expf(lg[r * N_LABELS + tid] - m);
    col[tid] = m + logf(s);
  }
  __syncthreads();
  for (int o = tid; o < N_GRAPHS * N_LABELS; o += 256) {
    int c = o % N_LABELS;
    out[o] = lg[o] - col[c];
  }
}

// ---------------- launch ----------------
extern "C" void kernel_launch(void* const* d_in, const int* in_sizes, int n_in,
                              void* d_out, int out_size, void* d_ws, size_t ws_size,
                              hipStream_t stream) {
  const int*   x     = (const int*)  d_in[0];
  const int*   ei    = (const int*)  d_in[1];
  const int*   batch = (const int*)  d_in[2];
  const float* emb   = (const float*)d_in[3];
  const float* w1rel = (const float*)d_in[4];
  const float* w1rt  = (const float*)d_in[5];
  const float* b1    = (const float*)d_in[6];
  const float* w2rel = (const float*)d_in[7];
  const float* w2rt  = (const float*)d_in[8];
  const float* b2    = (const float*)d_in[9];
  const float* lw1   = (const float*)d_in[10];
  const float* lb1   = (const float*)d_in[11];
  const float* lw2   = (const float*)d_in[12];
  const float* lb2   = (const float*)d_in[13];
  const float* lw3   = (const float*)d_in[14];
  const float* lb3   = (const float*)d_in[15];
  float* out = (float*)d_out;

  char* ws = (char*)d_ws;
  const size_t HB   = 51200000;    // N_NODES*FDIM*4
  const size_t CSRB = 6400128;     // (N_EDGES+8) ints
  const size_t OFFB = 400128;      // (N_NODES+1) ints, rounded
  float* hB      = (float*)(ws);
  // emb_bf aliases hB[0:12.8M]: dead before gemm1 writes hB
  unsigned short* embbf = (unsigned short*)(ws);
  float* aggbuf  = (float*)(ws + HB);
  // ebuf aliases aggbuf: dead before agg1 writes aggbuf
  int*   ebuf    = (int*)  (ws + HB);
  int*   csr     = (int*)  (ws + 2 * HB);
  // cntmat/S/bsum alias csr: dead before fill2 writes csr
  int*   cntmat  = (int*)  (ws + 2 * HB);
  int*   S       = (int*)  (ws + 2 * HB + 400128);
  int*   bsum    = (int*)  (ws + 2 * HB + 800256);
  int*   csr2    = (int*)  (ws + 2 * HB + CSRB);
  int*   offsets = (int*)  (ws + 2 * HB + 2 * CSRB);
  int*   bstart  = (int*)  (ws + 2 * HB + 2 * CSRB + OFFB);            // 6,400
  float* zrow    = (float*)(ws + 2 * HB + 2 * CSRB + OFFB + 6400);     // 512
  int*   start   = (int*)  (ws + 2 * HB + 2 * CSRB + OFFB + 6912);     // 512
  float* pool    = (float*)(ws + 2 * HB + 2 * CSRB + OFFB + 7424);     // 65,536
  float* t1      = (float*)(ws + 2 * HB + 2 * CSRB + OFFB + 72960);    // 32,768
  float* t2      = (float*)(ws + 2 * HB + 2 * CSRB + OFFB + 105728);   // 16,384
  unsigned short* hbf =
      (unsigned short*)(ws + 2 * HB + 2 * CSRB + OFFB + 122112);       // 25.6 MB

  init_kernel<<<64, 256, 0, stream>>>(pool, zrow, csr, csr2, offsets);

  cvt_emb_kernel<<<6250, 256, 0, stream>>>(emb, embbf);

  histA_kernel<<<NCHUNKS, 256, 0, stream>>>(ei, cntmat);
  scanB1_kernel<<<SB_BLOCKS, 256, 0, stream>>>(cntmat, S, bsum);
  scanB2_kernel<<<1, 512, 0, stream>>>(bsum);
  scanB3_kernel<<<SB_BLOCKS, 256, 0, stream>>>(S, bsum, bstart);
  scatA_kernel<<<NCHUNKS, 256, 0, stream>>>(ei, S, ebuf);
  fill2_kernel<<<P_BKT, 256, 0, stream>>>(ebuf, bstart, x, offsets, csr, csr2);

  // layer 1: aggregate bf16 emb rows via csr2 = x[src]; h-term via x (fp32)
  agg_kernel<true><<<N_NODES / 8, 256, 0, stream>>>(embbf, csr2, offsets, zrow,
                                                    aggbuf);
  gemm_kernel<<<(N_NODES + 127) / 128, 256, 0, stream>>>(
      aggbuf, emb, x, w1rel, w1rt, b1, hB, hbf);

  // layer 2: aggregate bf16 h1 rows via csr; in-place gemm on hB (fp32)
  agg_kernel<true><<<N_NODES / 8, 256, 0, stream>>>(hbf, csr, offsets, zrow,
                                                    aggbuf);
  gemm_kernel<<<(N_NODES + 127) / 128, 256, 0, stream>>>(
      aggbuf, hB, (const int*)nullptr, w2rel, w2rt, b2, hB,
      (unsigned short*)nullptr);

  find_starts_kernel<<<SB_BLOCKS, 256, 0, stream>>>(batch, start);
  pool_kernel<<<N_GRAPHS * 8, 128, 0, stream>>>(hB, start, pool);
  pool_fin_kernel<<<32, 256, 0, stream>>>(pool, start);

  head1_kernel<<<32, 256, 0, stream>>>(pool, lw1, lb1, t1);
  head2_kernel<<<16, 256, 0, stream>>>(t1, lw2, lb2, t2);
  head3_kernel<<<1, 256, 0, stream>>>(t2, lw3, lb3, out);
}

// Round 12
// 762.278 us; speedup vs baseline: 1.0181x; 1.0181x over previous
//
#include <hip/hip_runtime.h>
#include <hip/hip_bf16.h>

#define N_NODES   100000
#define N_EDGES   1600000
#define N_GRAPHS  64
#define FDIM      128
#define N_LABELS  20
#define NBK       64                  // nodes per dst-bucket
#define P_BKT     1563                // ceil(N_NODES/NBK)
#define NCHUNKS   64                  // edge chunks
#define CHUNK     25000               // N_EDGES / NCHUNKS
#define SCAN_M    (P_BKT * NCHUNKS)   // 100032
#define SB_BLOCKS 391                 // ceil(SCAN_M/256); also covers N_NODES

__device__ __forceinline__ unsigned bfr(float v) {   // fp32 -> bf16 (RTNE-ish)
  unsigned b = __float_as_uint(v);
  return (b + 0x7fffu + ((b >> 16) & 1u)) >> 16;
}

// ---------------- init: zero pool/zrow, csr pads, offsets[N] ----------------
__global__ __launch_bounds__(256) void init_kernel(
    float* __restrict__ pool, float* __restrict__ zrow,
    int* __restrict__ csr, int* __restrict__ csr2, int* __restrict__ offsets) {
  int i = blockIdx.x * 256 + threadIdx.x;
  if (i < N_GRAPHS * 256) pool[i] = 0.f;
  if (i < FDIM) zrow[i] = 0.f;
  if (i < 8) { csr[N_EDGES + i] = 0; csr2[N_EDGES + i] = 0; }
  if (i == 8) offsets[N_NODES] = N_EDGES;
}

// ---------------- emb -> bf16 (12.8 MB) ----------------
__global__ __launch_bounds__(256) void cvt_emb_kernel(
    const float* __restrict__ emb, unsigned short* __restrict__ embbf) {
  int i = blockIdx.x * 256 + threadIdx.x;   // quad id, 1,600,000 total
  float4 v = ((const float4*)emb)[i];
  uint2 o;
  o.x = bfr(v.x) | (bfr(v.y) << 16);
  o.y = bfr(v.z) | (bfr(v.w) << 16);
  ((uint2*)embbf)[i] = o;
}

// ---------------- A1: per-chunk bucket histogram ----------------
__global__ __launch_bounds__(256) void histA_kernel(
    const int* __restrict__ ei, int* __restrict__ cntmat) {
  __shared__ int hist[P_BKT];
  int tid = threadIdx.x;
  for (int i = tid; i < P_BKT; i += 256) hist[i] = 0;
  __syncthreads();
  int base = blockIdx.x * CHUNK;
  for (int i = tid; i < CHUNK; i += 256) {
    int d = ei[N_EDGES + base + i];
    atomicAdd(&hist[d >> 6], 1);
  }
  __syncthreads();
  for (int p = tid; p < P_BKT; p += 256)
    cntmat[p * NCHUNKS + blockIdx.x] = hist[p];
}

// ---------------- A2: 3-level exclusive scan over cntmat (bucket-major) -----
__global__ __launch_bounds__(256) void scanB1_kernel(
    const int* __restrict__ v, int* __restrict__ part,
    int* __restrict__ bsum) {
  __shared__ int s[256];
  int tid = threadIdx.x;
  int i = blockIdx.x * 256 + tid;
  int val = (i < SCAN_M) ? v[i] : 0;
  s[tid] = val;
  __syncthreads();
  for (int off = 1; off < 256; off <<= 1) {
    int t = (tid >= off) ? s[tid - off] : 0;
    __syncthreads();
    s[tid] += t;
    __syncthreads();
  }
  if (i < SCAN_M) part[i] = s[tid] - val;
  if (tid == 255) bsum[blockIdx.x] = s[255];
}

__global__ __launch_bounds__(512) void scanB2_kernel(int* __restrict__ bsum) {
  __shared__ int s[512];
  int tid = threadIdx.x;
  int v = (tid < SB_BLOCKS) ? bsum[tid] : 0;
  s[tid] = v;
  __syncthreads();
  for (int off = 1; off < 512; off <<= 1) {
    int t = (tid >= off) ? s[tid - off] : 0;
    __syncthreads();
    s[tid] += t;
    __syncthreads();
  }
  if (tid < SB_BLOCKS) bsum[tid] = s[tid] - v;
}

__global__ __launch_bounds__(256) void scanB3_kernel(
    int* __restrict__ part, const int* __restrict__ bsum,
    int* __restrict__ bstart) {
  int i = blockIdx.x * 256 + threadIdx.x;
  if (i < SCAN_M) {
    int o = part[i] + bsum[blockIdx.x];
    part[i] = o;
    if ((i & (NCHUNKS - 1)) == 0) bstart[i >> 6] = o;
  }
  if (blockIdx.x == 0 && threadIdx.x == 0) bstart[P_BKT] = N_EDGES;
}

// ---------------- A3: scatter edges grouped by bucket (packed src<<6|ldst) --
__global__ __launch_bounds__(256) void scatA_kernel(
    const int* __restrict__ ei, const int* __restrict__ S,
    int* __restrict__ ebuf) {
  __shared__ int rc[P_BKT];
  int tid = threadIdx.x;
  for (int p = tid; p < P_BKT; p += 256)
    rc[p] = S[p * NCHUNKS + blockIdx.x];
  __syncthreads();
  int base = blockIdx.x * CHUNK;
  for (int i = tid; i < CHUNK; i += 256) {
    int s0 = ei[base + i];
    int d0 = ei[N_EDGES + base + i];
    int pos = atomicAdd(&rc[d0 >> 6], 1);
    ebuf[pos] = (s0 << 6) | (d0 & 63);
  }
}

// ---------------- A4: per-bucket CSR build (single-writer csr window) -------
__global__ __launch_bounds__(256) void fill2_kernel(
    const int* __restrict__ ebuf, const int* __restrict__ bstart,
    const int* __restrict__ x, int* __restrict__ offsets,
    int* __restrict__ csr, int* __restrict__ csr2) {
  __shared__ int ldeg[NBK], loffs[NBK], rc2[NBK];
  int tid = threadIdx.x;
  int p = blockIdx.x;
  int beg = bstart[p], end = bstart[p + 1];
  if (tid < NBK) ldeg[tid] = 0;
  __syncthreads();
  for (int i = beg + tid; i < end; i += 256)
    atomicAdd(&ldeg[ebuf[i] & 63], 1);
  __syncthreads();
  if (tid == 0) {
    int run = 0;
    for (int r = 0; r < NBK; ++r) { loffs[r] = run; run += ldeg[r]; }
  }
  __syncthreads();
  if (tid < NBK) {
    rc2[tid] = loffs[tid];
    int gn = p * NBK + tid;
    if (gn < N_NODES) offsets[gn] = beg + loffs[tid];
  }
  __syncthreads();
  for (int i = beg + tid; i < end; i += 256) {
    int e = ebuf[i];
    int ld = e & 63;
    int src = e >> 6;
    int pos = atomicAdd(&rc2[ld], 1);
    csr[beg + pos] = src;
    csr2[beg + pos] = x[src];
  }
}

// ---------------- aggregation: agg[i,:] = sum_{j->i} feat[srcidx[j],:] ------
// BF16=true: feat is bf16 rows (256 B), lane reads uint2, converts, fp32 acc.
template <bool BF16>
__global__ __launch_bounds__(256) void agg_kernel(
    const void* __restrict__ feat, const int* __restrict__ srcidx,
    const int* __restrict__ offs, const float* __restrict__ zrow,
    float* __restrict__ aggout) {
  int sub = threadIdx.x >> 5;
  int fq  = threadIdx.x & 31;
  int node = blockIdx.x * 8 + sub;

  float4 acc0 = make_float4(0.f, 0.f, 0.f, 0.f);
  float4 acc1 = make_float4(0.f, 0.f, 0.f, 0.f);
  int s = offs[node], e = offs[node + 1];

  if constexpr (BF16) {
    const uint2* __restrict__ fb = (const uint2*)feat;
    const uint2* __restrict__ zb = (const uint2*)zrow;  // 256 B of zero bits
    for (int p = s; p < e; p += 8) {
      const uint2* rp[8];
#pragma unroll
      for (int u = 0; u < 8; ++u) {
        int iu = srcidx[p + u];                       // safe: padded by 8
        rp[u] = (p + u < e) ? (fb + (size_t)iu * 32) : zb;
      }
      uint2 w[8];
#pragma unroll
      for (int u = 0; u < 8; ++u) w[u] = rp[u][fq];
#pragma unroll
      for (int u = 0; u < 8; ++u) {
        float4& A = (u & 1) ? acc1 : acc0;
        A.x += __uint_as_float(w[u].x << 16);
        A.y += __uint_as_float(w[u].x & 0xffff0000u);
        A.z += __uint_as_float(w[u].y << 16);
        A.w += __uint_as_float(w[u].y & 0xffff0000u);
      }
    }
  } else {
    const float4* __restrict__ f4 = (const float4*)feat;
    const float4* __restrict__ z4 = (const float4*)zrow;
    for (int p = s; p < e; p += 8) {
      const float4* rp[8];
#pragma unroll
      for (int u = 0; u < 8; ++u) {
        int iu = srcidx[p + u];
        rp[u] = (p + u < e) ? (f4 + (size_t)iu * 32) : z4;
      }
      float4 v[8];
#pragma unroll
      for (int u = 0; u < 8; ++u) v[u] = rp[u][fq];
#pragma unroll
      for (int u = 0; u < 8; ++u) {
        float4& A = (u & 1) ? acc1 : acc0;
        A.x += v[u].x; A.y += v[u].y; A.z += v[u].z; A.w += v[u].w;
      }
    }
  }
  float4 a = make_float4(acc0.x + acc1.x, acc0.y + acc1.y,
                         acc0.z + acc1.z, acc0.w + acc1.w);
  ((float4*)aggout)[(size_t)node * 32 + fq] = a;
}

// ---------------- GEMM: hout = relu([agg | h] @ [wrel; wroot] + b) ----------
// R6 core + R11 register prefetch of tile t+1. R12: __launch_bounds__(256,3)
// raises the VGPR cap to ~170 so the prefetch lives in registers (R11 kept
// VGPR=80 and spilled 179 MB of scratch — the +197 MB WRITE_SIZE delta).
__global__ __launch_bounds__(256, 3) void gemm_kernel(
    const float* __restrict__ agg, const float* __restrict__ hsrc,
    const int* __restrict__ hidx,
    const float* __restrict__ wrel, const float* __restrict__ wroot,
    const float* __restrict__ bias, float* __restrict__ hout,
    unsigned short* __restrict__ hbf) {
  __shared__ float A_s[128 * 32];
  __shared__ float W_s[32 * 128];
  int tid = threadIdx.x;
  int nodeBase = blockIdx.x * 128;
  int tc = tid & 15, tr = tid >> 4;

  int a_gn[4], a_hr[4], a_q[4], a_lds[4];
#pragma unroll
  for (int i = 0; i < 4; ++i) {
    int f = tid + 256 * i;
    int n = f >> 3, q = f & 7;
    int gn = nodeBase + n;
    if (gn > N_NODES - 1) gn = N_NODES - 1;
    a_gn[i] = gn;
    a_hr[i] = hidx ? hidx[gn] : gn;
    a_q[i] = q;
    a_lds[i] = n * 32 + ((q * 4) ^ (4 * ((n >> 3) & 7)));
  }
  int wk[4], wq[4];
#pragma unroll
  for (int i = 0; i < 4; ++i) {
    int f = tid + 256 * i;
    wk[i] = f >> 5;
    wq[i] = f & 31;
  }

  float acc[8][8];
  {
    float4 b0 = *(const float4*)&bias[4 * tc];
    float4 b1 = *(const float4*)&bias[64 + 4 * tc];
#pragma unroll
    for (int i = 0; i < 8; ++i) {
      acc[i][0] = b0.x; acc[i][1] = b0.y; acc[i][2] = b0.z; acc[i][3] = b0.w;
      acc[i][4] = b1.x; acc[i][5] = b1.y; acc[i][6] = b1.z; acc[i][7] = b1.w;
    }
  }

  const int kx_base = 4 * (tr & 7);

  // prefetch tile 0
  float4 pa[4], pw[4];
#pragma unroll
  for (int i = 0; i < 4; ++i) {
    pa[i] = *(const float4*)(agg + (size_t)a_gn[i] * FDIM + a_q[i] * 4);
    pw[i] = *(const float4*)(wrel + (size_t)wk[i] * FDIM + wq[i] * 4);
  }

#pragma unroll 1
  for (int t = 0; t < 8; ++t) {
    __syncthreads();
#pragma unroll
    for (int i = 0; i < 4; ++i) {
      *(float4*)&A_s[a_lds[i]] = pa[i];
      *(float4*)&W_s[wk[i] * 128 + wq[i] * 4] = pw[i];
    }
    __syncthreads();
    if (t < 7) {
      int tn = t + 1;
#pragma unroll
      for (int i = 0; i < 4; ++i) {
        const float* srcA = (tn < 4)
            ? (agg  + (size_t)a_gn[i] * FDIM + tn * 32 + a_q[i] * 4)
            : (hsrc + (size_t)a_hr[i] * FDIM + (tn - 4) * 32 + a_q[i] * 4);
        pa[i] = *(const float4*)srcA;
        const float* W = (tn < 4) ? (wrel + (size_t)(tn * 32) * FDIM)
                                  : (wroot + (size_t)((tn - 4) * 32) * FDIM);
        pw[i] = *(const float4*)(W + (size_t)wk[i] * FDIM + wq[i] * 4);
      }
    }

#pragma unroll 1
    for (int k0 = 0; k0 < 32; k0 += 4) {
      float4 a4[8];
      int kx = k0 ^ kx_base;
#pragma unroll
      for (int i = 0; i < 8; ++i)
        a4[i] = *(const float4*)&A_s[(8 * tr + i) * 32 + kx];
#pragma unroll
      for (int kk = 0; kk < 4; ++kk) {
        float4 w0 = *(const float4*)&W_s[(k0 + kk) * 128 + 4 * tc];
        float4 w1 = *(const float4*)&W_s[(k0 + kk) * 128 + 64 + 4 * tc];
#pragma unroll
        for (int i = 0; i < 8; ++i) {
          float a = (kk == 0) ? a4[i].x : (kk == 1) ? a4[i].y
                  : (kk == 2) ? a4[i].z : a4[i].w;
          acc[i][0] += a * w0.x; acc[i][1] += a * w0.y;
          acc[i][2] += a * w0.z; acc[i][3] += a * w0.w;
          acc[i][4] += a * w1.x; acc[i][5] += a * w1.y;
          acc[i][6] += a * w1.z; acc[i][7] += a * w1.w;
        }
      }
    }
  }

#pragma unroll
  for (int i = 0; i < 8; ++i) {
    int n = nodeBase + tr * 8 + i;
    if (n < N_NODES) {
      float* o = hout + (size_t)n * FDIM;
      float4 v0, v1;
      v0.x = fmaxf(acc[i][0], 0.f); v0.y = fmaxf(acc[i][1], 0.f);
      v0.z = fmaxf(acc[i][2], 0.f); v0.w = fmaxf(acc[i][3], 0.f);
      v1.x = fmaxf(acc[i][4], 0.f); v1.y = fmaxf(acc[i][5], 0.f);
      v1.z = fmaxf(acc[i][6], 0.f); v1.w = fmaxf(acc[i][7], 0.f);
      *(float4*)(o + 4 * tc) = v0;
      *(float4*)(o + 64 + 4 * tc) = v1;
      if (hbf) {
        unsigned short* ob = hbf + (size_t)n * FDIM;
        uint2 p0, p1;
        p0.x = bfr(v0.x) | (bfr(v0.y) << 16);
        p0.y = bfr(v0.z) | (bfr(v0.w) << 16);
        p1.x = bfr(v1.x) | (bfr(v1.y) << 16);
        p1.y = bfr(v1.z) | (bfr(v1.w) << 16);
        *(uint2*)(ob + 4 * tc) = p0;
        *(uint2*)(ob + 64 + 4 * tc) = p1;
      }
    }
  }
}

// ---------------- per-graph segment boundaries (batch is sorted) ------------
__global__ void find_starts_kernel(const int* __restrict__ batch,
                                   int* __restrict__ start) {
  int i = blockIdx.x * 256 + threadIdx.x;
  if (i >= N_NODES) return;
  int b  = batch[i];
  int bp = (i == 0) ? -1 : batch[i - 1];
  for (int g = bp + 1; g <= b; ++g) start[g] = i;
  if (i == N_NODES - 1) {
    for (int g = b + 1; g <= N_GRAPHS; ++g) start[g] = N_NODES;
  }
}

// ---------------- pooling: max & sum per graph ----------------
__global__ __launch_bounds__(128) void pool_kernel(
    const float* __restrict__ h2, const int* __restrict__ start,
    float* __restrict__ pool) {
  int g = blockIdx.x >> 3;
  int c = blockIdx.x & 7;
  int f = threadIdx.x;
  int s = start[g], e = start[g + 1];
  int len = e - s;
  int lo = s + (int)(((long long)len * c) >> 3);
  int hi = s + (int)(((long long)len * (c + 1)) >> 3);
  float mx = 0.f, sm = 0.f;
  for (int n = lo; n < hi; ++n) {
    float v = h2[(size_t)n * FDIM + f];
    mx = fmaxf(mx, v);
    sm += v;
  }
  atomicMax((unsigned int*)&pool[g * 256 + f], __float_as_uint(mx));
  atomicAdd(&pool[g * 256 + 128 + f], sm);
}

__global__ void pool_fin_kernel(float* __restrict__ pool,
                                const int* __restrict__ start) {
  int gid = blockIdx.x * 256 + threadIdx.x;   // 8192
  int g = gid >> 7, f = gid & 127;
  int cnt = start[g + 1] - start[g];
  float c = (float)(cnt > 1 ? cnt : 1);
  pool[g * 256 + 128 + f] /= c;
}

// ---------------- MLP head ----------------
__global__ void head1_kernel(const float* __restrict__ pool,
                             const float* __restrict__ lw1,
                             const float* __restrict__ lb1,
                             float* __restrict__ t1) {
  int gid = blockIdx.x * 256 + threadIdx.x;   // 8192
  int r = gid >> 7, c = gid & 127;
  float acc = lb1[c];
  for (int k = 0; k < 256; ++k) acc += pool[r * 256 + k] * lw1[k * 128 + c];
  t1[gid] = fmaxf(acc, 0.f);
}

__global__ void head2_kernel(const float* __restrict__ t1,
                             const float* __restrict__ lw2,
                             const float* __restrict__ lb2,
                             float* __restrict__ t2) {
  int gid = blockIdx.x * 256 + threadIdx.x;   // 4096
  int r = gid >> 6, c = gid & 63;
  float acc = lb2[c];
  for (int k = 0; k < 128; ++k) acc += t1[r * 128 + k] * lw2[k * 64 + c];
  t2[gid] = fmaxf(acc, 0.f);
}

__global__ __launch_bounds__(256) void head3_kernel(
    const float* __restrict__ t2, const float* __restrict__ lw3,
    const float* __restrict__ lb3, float* __restrict__ out) {
  __shared__ float lg[N_GRAPHS * N_LABELS];
  __shared__ float col[N_LABELS];
  int tid = threadIdx.x;
  for (int o = tid; o < N_GRAPHS * N_LABELS; o += 256) {
    int r = o / N_LABELS, c = o - r * N_LABELS;
    float acc = lb3[c];
    for (int k = 0; k < 64; ++k) acc += t2[r * 64 + k] * lw3[k * N_LABELS + c];
    lg[o] = acc;
  }
  __syncthreads();
  if (tid < N_LABELS) {
    float m = -1e30f;
    for (int r = 0; r < N_GRAPHS; ++r) m = fmaxf(m, lg[r * N_LABELS + tid]);
    float s = 0.f;
    for (int r = 0; r < N_GRAPHS; ++r) s += expf(lg[r * N_LABELS + tid] - m);
    col[tid] = m + logf(s);
  }
  __syncthreads();
  for (int o = tid; o < N_GRAPHS * N_LABELS; o += 256) {
    int c = o % N_LABELS;
    out[o] = lg[o] - col[c];
  }
}

// ---------------- launch ----------------
extern "C" void kernel_launch(void* const* d_in, const int* in_sizes, int n_in,
                              void* d_out, int out_size, void* d_ws, size_t ws_size,
                              hipStream_t stream) {
  const int*   x     = (const int*)  d_in[0];
  const int*   ei    = (const int*)  d_in[1];
  const int*   batch = (const int*)  d_in[2];
  const float* emb   = (const float*)d_in[3];
  const float* w1rel = (const float*)d_in[4];
  const float* w1rt  = (const float*)d_in[5];
  const float* b1    = (const float*)d_in[6];
  const float* w2rel = (const float*)d_in[7];
  const float* w2rt  = (const float*)d_in[8];
  const float* b2    = (const float*)d_in[9];
  const float* lw1   = (const float*)d_in[10];
  const float* lb1   = (const float*)d_in[11];
  const float* lw2   = (const float*)d_in[12];
  const float* lb2   = (const float*)d_in[13];
  const float* lw3   = (const float*)d_in[14];
  const float* lb3   = (const float*)d_in[15];
  float* out = (float*)d_out;

  char* ws = (char*)d_ws;
  const size_t HB   = 51200000;    // N_NODES*FDIM*4
  const size_t CSRB = 6400128;     // (N_EDGES+8) ints
  const size_t OFFB = 400128;      // (N_NODES+1) ints, rounded
  float* hB      = (float*)(ws);
  // emb_bf aliases hB[0:12.8M]: dead before gemm1 writes hB
  unsigned short* embbf = (unsigned short*)(ws);
  float* aggbuf  = (float*)(ws + HB);
  // ebuf aliases aggbuf: dead before agg1 writes aggbuf
  int*   ebuf    = (int*)  (ws + HB);
  int*   csr     = (int*)  (ws + 2 * HB);
  // cntmat/S/bsum alias csr: dead before fill2 writes csr
  int*   cntmat  = (int*)  (ws + 2 * HB);
  int*   S       = (int*)  (ws + 2 * HB + 400128);
  int*   bsum    = (int*)  (ws + 2 * HB + 800256);
  int*   csr2    = (int*)  (ws + 2 * HB + CSRB);
  int*   offsets = (int*)  (ws + 2 * HB + 2 * CSRB);
  int*   bstart  = (int*)  (ws + 2 * HB + 2 * CSRB + OFFB);            // 6,400
  float* zrow    = (float*)(ws + 2 * HB + 2 * CSRB + OFFB + 6400);     // 512
  int*   start   = (int*)  (ws + 2 * HB + 2 * CSRB + OFFB + 6912);     // 512
  float* pool    = (float*)(ws + 2 * HB + 2 * CSRB + OFFB + 7424);     // 65,536
  float* t1      = (float*)(ws + 2 * HB + 2 * CSRB + OFFB + 72960);    // 32,768
  float* t2      = (float*)(ws + 2 * HB + 2 * CSRB + OFFB + 105728);   // 16,384
  unsigned short* hbf =
      (unsigned short*)(ws + 2 * HB + 2 * CSRB + OFFB + 122112);       // 25.6 MB

  init_kernel<<<64, 256, 0, stream>>>(pool, zrow, csr, csr2, offsets);

  cvt_emb_kernel<<<6250, 256, 0, stream>>>(emb, embbf);

  histA_kernel<<<NCHUNKS, 256, 0, stream>>>(ei, cntmat);
  scanB1_kernel<<<SB_BLOCKS, 256, 0, stream>>>(cntmat, S, bsum);
  scanB2_kernel<<<1, 512, 0, stream>>>(bsum);
  scanB3_kernel<<<SB_BLOCKS, 256, 0, stream>>>(S, bsum, bstart);
  scatA_kernel<<<NCHUNKS, 256, 0, stream>>>(ei, S, ebuf);
  fill2_kernel<<<P_BKT, 256, 0, stream>>>(ebuf, bstart, x, offsets, csr, csr2);

  // layer 1: aggregate bf16 emb rows via csr2 = x[src]; h-term via x (fp32)
  agg_kernel<true><<<N_NODES / 8, 256, 0, stream>>>(embbf, csr2, offsets, zrow,
                                                    aggbuf);
  gemm_kernel<<<(N_NODES + 127) / 128, 256, 0, stream>>>(
      aggbuf, emb, x, w1rel, w1rt, b1, hB, hbf);

  // layer 2: aggregate bf16 h1 rows via csr; in-place gemm on hB (fp32)
  agg_kernel<true><<<N_NODES / 8, 256, 0, stream>>>(hbf, csr, offsets, zrow,
                                                    aggbuf);
  gemm_kernel<<<(N_NODES + 127) / 128, 256, 0, stream>>>(
      aggbuf, hB, (const int*)nullptr, w2rel, w2rt, b2, hB,
      (unsigned short*)nullptr);

  find_starts_kernel<<<SB_BLOCKS, 256, 0, stream>>>(batch, start);
  pool_kernel<<<N_GRAPHS * 8, 128, 0, stream>>>(hB, start, pool);
  pool_fin_kernel<<<32, 256, 0, stream>>>(pool, start);

  head1_kernel<<<32, 256, 0, stream>>>(pool, lw1, lb1, t1);
  head2_kernel<<<16, 256, 0, stream>>>(t1, lw2, lb2, t2);
  head3_kernel<<<1, 256, 0, stream>>>(t2, lw3, lb3, out);
}

// Round 13
// 653.292 us; speedup vs baseline: 1.1879x; 1.1668x over previous
//
#include <hip/hip_runtime.h>
#include <hip/hip_bf16.h>

#define N_NODES   100000
#define N_EDGES   1600000
#define N_GRAPHS  64
#define FDIM      128
#define N_LABELS  20
#define NBK       64                  // nodes per dst-bucket
#define P_BKT     1563                // ceil(N_NODES/NBK)
#define NCHUNKS   64                  // edge chunks
#define CHUNK     25000               // N_EDGES / NCHUNKS
#define SCAN_M    (P_BKT * NCHUNKS)   // 100032
#define SB_BLOCKS 391                 // ceil(SCAN_M/256); also covers N_NODES

typedef const __attribute__((address_space(1))) void* gptr_t;
typedef __attribute__((address_space(3))) void* lptr_t;

__device__ __forceinline__ unsigned bfr(float v) {   // fp32 -> bf16 (RTNE-ish)
  unsigned b = __float_as_uint(v);
  return (b + 0x7fffu + ((b >> 16) & 1u)) >> 16;
}

// ---------------- init: zero pool/zrow, csr pads, offsets[N] ----------------
__global__ __launch_bounds__(256) void init_kernel(
    float* __restrict__ pool, float* __restrict__ zrow,
    int* __restrict__ csr, int* __restrict__ csr2, int* __restrict__ offsets) {
  int i = blockIdx.x * 256 + threadIdx.x;
  if (i < N_GRAPHS * 256) pool[i] = 0.f;
  if (i < FDIM) zrow[i] = 0.f;
  if (i < 8) { csr[N_EDGES + i] = 0; csr2[N_EDGES + i] = 0; }
  if (i == 8) offsets[N_NODES] = N_EDGES;
}

// ---------------- emb -> bf16 (12.8 MB) ----------------
__global__ __launch_bounds__(256) void cvt_emb_kernel(
    const float* __restrict__ emb, unsigned short* __restrict__ embbf) {
  int i = blockIdx.x * 256 + threadIdx.x;   // quad id, 1,600,000 total
  float4 v = ((const float4*)emb)[i];
  uint2 o;
  o.x = bfr(v.x) | (bfr(v.y) << 16);
  o.y = bfr(v.z) | (bfr(v.w) << 16);
  ((uint2*)embbf)[i] = o;
}

// ---------------- A1: per-chunk bucket histogram ----------------
__global__ __launch_bounds__(256) void histA_kernel(
    const int* __restrict__ ei, int* __restrict__ cntmat) {
  __shared__ int hist[P_BKT];
  int tid = threadIdx.x;
  for (int i = tid; i < P_BKT; i += 256) hist[i] = 0;
  __syncthreads();
  int base = blockIdx.x * CHUNK;
  for (int i = tid; i < CHUNK; i += 256) {
    int d = ei[N_EDGES + base + i];
    atomicAdd(&hist[d >> 6], 1);
  }
  __syncthreads();
  for (int p = tid; p < P_BKT; p += 256)
    cntmat[p * NCHUNKS + blockIdx.x] = hist[p];
}

// ---------------- A2: 3-level exclusive scan over cntmat (bucket-major) -----
__global__ __launch_bounds__(256) void scanB1_kernel(
    const int* __restrict__ v, int* __restrict__ part,
    int* __restrict__ bsum) {
  __shared__ int s[256];
  int tid = threadIdx.x;
  int i = blockIdx.x * 256 + tid;
  int val = (i < SCAN_M) ? v[i] : 0;
  s[tid] = val;
  __syncthreads();
  for (int off = 1; off < 256; off <<= 1) {
    int t = (tid >= off) ? s[tid - off] : 0;
    __syncthreads();
    s[tid] += t;
    __syncthreads();
  }
  if (i < SCAN_M) part[i] = s[tid] - val;
  if (tid == 255) bsum[blockIdx.x] = s[255];
}

__global__ __launch_bounds__(512) void scanB2_kernel(int* __restrict__ bsum) {
  __shared__ int s[512];
  int tid = threadIdx.x;
  int v = (tid < SB_BLOCKS) ? bsum[tid] : 0;
  s[tid] = v;
  __syncthreads();
  for (int off = 1; off < 512; off <<= 1) {
    int t = (tid >= off) ? s[tid - off] : 0;
    __syncthreads();
    s[tid] += t;
    __syncthreads();
  }
  if (tid < SB_BLOCKS) bsum[tid] = s[tid] - v;
}

__global__ __launch_bounds__(256) void scanB3_kernel(
    int* __restrict__ part, const int* __restrict__ bsum,
    int* __restrict__ bstart) {
  int i = blockIdx.x * 256 + threadIdx.x;
  if (i < SCAN_M) {
    int o = part[i] + bsum[blockIdx.x];
    part[i] = o;
    if ((i & (NCHUNKS - 1)) == 0) bstart[i >> 6] = o;
  }
  if (blockIdx.x == 0 && threadIdx.x == 0) bstart[P_BKT] = N_EDGES;
}

// ---------------- A3: scatter edges grouped by bucket (packed src<<6|ldst) --
__global__ __launch_bounds__(256) void scatA_kernel(
    const int* __restrict__ ei, const int* __restrict__ S,
    int* __restrict__ ebuf) {
  __shared__ int rc[P_BKT];
  int tid = threadIdx.x;
  for (int p = tid; p < P_BKT; p += 256)
    rc[p] = S[p * NCHUNKS + blockIdx.x];
  __syncthreads();
  int base = blockIdx.x * CHUNK;
  for (int i = tid; i < CHUNK; i += 256) {
    int s0 = ei[base + i];
    int d0 = ei[N_EDGES + base + i];
    int pos = atomicAdd(&rc[d0 >> 6], 1);
    ebuf[pos] = (s0 << 6) | (d0 & 63);
  }
}

// ---------------- A4: per-bucket CSR build (single-writer csr window) -------
__global__ __launch_bounds__(256) void fill2_kernel(
    const int* __restrict__ ebuf, const int* __restrict__ bstart,
    const int* __restrict__ x, int* __restrict__ offsets,
    int* __restrict__ csr, int* __restrict__ csr2) {
  __shared__ int ldeg[NBK], loffs[NBK], rc2[NBK];
  int tid = threadIdx.x;
  int p = blockIdx.x;
  int beg = bstart[p], end = bstart[p + 1];
  if (tid < NBK) ldeg[tid] = 0;
  __syncthreads();
  for (int i = beg + tid; i < end; i += 256)
    atomicAdd(&ldeg[ebuf[i] & 63], 1);
  __syncthreads();
  if (tid == 0) {
    int run = 0;
    for (int r = 0; r < NBK; ++r) { loffs[r] = run; run += ldeg[r]; }
  }
  __syncthreads();
  if (tid < NBK) {
    rc2[tid] = loffs[tid];
    int gn = p * NBK + tid;
    if (gn < N_NODES) offsets[gn] = beg + loffs[tid];
  }
  __syncthreads();
  for (int i = beg + tid; i < end; i += 256) {
    int e = ebuf[i];
    int ld = e & 63;
    int src = e >> 6;
    int pos = atomicAdd(&rc2[ld], 1);
    csr[beg + pos] = src;
    csr2[beg + pos] = x[src];
  }
}

// ---------------- aggregation: agg[i,:] = sum_{j->i} feat[srcidx[j],:] ------
// BF16=true: feat is bf16 rows (256 B), lane reads uint2, converts, fp32 acc.
template <bool BF16>
__global__ __launch_bounds__(256) void agg_kernel(
    const void* __restrict__ feat, const int* __restrict__ srcidx,
    const int* __restrict__ offs, const float* __restrict__ zrow,
    float* __restrict__ aggout) {
  int sub = threadIdx.x >> 5;
  int fq  = threadIdx.x & 31;
  int node = blockIdx.x * 8 + sub;

  float4 acc0 = make_float4(0.f, 0.f, 0.f, 0.f);
  float4 acc1 = make_float4(0.f, 0.f, 0.f, 0.f);
  int s = offs[node], e = offs[node + 1];

  if constexpr (BF16) {
    const uint2* __restrict__ fb = (const uint2*)feat;
    const uint2* __restrict__ zb = (const uint2*)zrow;  // 256 B of zero bits
    for (int p = s; p < e; p += 8) {
      const uint2* rp[8];
#pragma unroll
      for (int u = 0; u < 8; ++u) {
        int iu = srcidx[p + u];                       // safe: padded by 8
        rp[u] = (p + u < e) ? (fb + (size_t)iu * 32) : zb;
      }
      uint2 w[8];
#pragma unroll
      for (int u = 0; u < 8; ++u) w[u] = rp[u][fq];
#pragma unroll
      for (int u = 0; u < 8; ++u) {
        float4& A = (u & 1) ? acc1 : acc0;
        A.x += __uint_as_float(w[u].x << 16);
        A.y += __uint_as_float(w[u].x & 0xffff0000u);
        A.z += __uint_as_float(w[u].y << 16);
        A.w += __uint_as_float(w[u].y & 0xffff0000u);
      }
    }
  } else {
    const float4* __restrict__ f4 = (const float4*)feat;
    const float4* __restrict__ z4 = (const float4*)zrow;
    for (int p = s; p < e; p += 8) {
      const float4* rp[8];
#pragma unroll
      for (int u = 0; u < 8; ++u) {
        int iu = srcidx[p + u];
        rp[u] = (p + u < e) ? (f4 + (size_t)iu * 32) : z4;
      }
      float4 v[8];
#pragma unroll
      for (int u = 0; u < 8; ++u) v[u] = rp[u][fq];
#pragma unroll
      for (int u = 0; u < 8; ++u) {
        float4& A = (u & 1) ? acc1 : acc0;
        A.x += v[u].x; A.y += v[u].y; A.z += v[u].z; A.w += v[u].w;
      }
    }
  }
  float4 a = make_float4(acc0.x + acc1.x, acc0.y + acc1.y,
                         acc0.z + acc1.z, acc0.w + acc1.w);
  ((float4*)aggout)[(size_t)node * 32 + fq] = a;
}

// ---------------- GEMM: hout = relu([agg | h] @ [wrel; wroot] + b) ----------
// R13: double-buffered LDS + async global_load_lds (width 16) staging.
// Tile t+1's DMA is issued before tile t's k-loop; the vmcnt(0) the compiler
// emits before the end-of-tile barrier lands after ~2000 cyc of FMA.
// A_s is plain row-major pitch 32 (lane-linear, DMA-compatible); A-reads are
// 4-way bank-aliased (1.58x on those instrs) — acceptable, VALU still poles.
__global__ __launch_bounds__(256) void gemm_kernel(
    const float* __restrict__ agg, const float* __restrict__ hsrc,
    const int* __restrict__ hidx,
    const float* __restrict__ wrel, const float* __restrict__ wroot,
    const float* __restrict__ bias, float* __restrict__ hout,
    unsigned short* __restrict__ hbf) {
  __shared__ float A_s[2][128 * 32];
  __shared__ float W_s[2][32 * 128];
  int tid = threadIdx.x;
  int nodeBase = blockIdx.x * 128;
  int tc = tid & 15, tr = tid >> 4;

  // staging descriptors: slot i covers f = tid + 256*i (0..1023)
  // A: n = f>>3, q = f&7 ; LDS dst = f*16 B (row-major pitch 32, lane-linear)
  // W: linear f*16 B on both sides
  const float* a_src[4];   // base row pointer (agg side)
  const float* h_src[4];   // base row pointer (hsrc side)
#pragma unroll
  for (int i = 0; i < 4; ++i) {
    int f = tid + 256 * i;
    int n = f >> 3, q = f & 7;
    int gn = nodeBase + n;
    if (gn > N_NODES - 1) gn = N_NODES - 1;
    int hr = hidx ? hidx[gn] : gn;
    a_src[i] = agg + (size_t)gn * FDIM + q * 4;
    h_src[i] = hsrc + (size_t)hr * FDIM + q * 4;
  }

  float acc[8][8];
  {
    float4 b0 = *(const float4*)&bias[4 * tc];
    float4 b1 = *(const float4*)&bias[64 + 4 * tc];
#pragma unroll
    for (int i = 0; i < 8; ++i) {
      acc[i][0] = b0.x; acc[i][1] = b0.y; acc[i][2] = b0.z; acc[i][3] = b0.w;
      acc[i][4] = b1.x; acc[i][5] = b1.y; acc[i][6] = b1.z; acc[i][7] = b1.w;
    }
  }

  // async stage of tile t into buffer b
  auto stage = [&](int t, int b) {
#pragma unroll
    for (int i = 0; i < 4; ++i) {
      int f = tid + 256 * i;
      const float* srcA = (t < 4) ? (a_src[i] + t * 32)
                                  : (h_src[i] + (t - 4) * 32);
      __builtin_amdgcn_global_load_lds((gptr_t)srcA,
                                       (lptr_t)&A_s[b][f * 4], 16, 0, 0);
    }
    const float* W = (t < 4) ? (wrel + (size_t)(t * 32) * FDIM)
                             : (wroot + (size_t)((t - 4) * 32) * FDIM);
#pragma unroll
    for (int i = 0; i < 4; ++i) {
      int f = tid + 256 * i;
      __builtin_amdgcn_global_load_lds((gptr_t)(W + f * 4),
                                       (lptr_t)&W_s[b][f * 4], 16, 0, 0);
    }
  };

  stage(0, 0);
  __syncthreads();   // compiler inserts vmcnt(0) before the barrier

#pragma unroll 1
  for (int t = 0; t < 8; ++t) {
    int cur = t & 1;
    if (t < 7) stage(t + 1, cur ^ 1);   // async DMA into the other buffer

#pragma unroll 1
    for (int k0 = 0; k0 < 32; k0 += 4) {
      float4 a4[8];
#pragma unroll
      for (int i = 0; i < 8; ++i)
        a4[i] = *(const float4*)&A_s[cur][(8 * tr + i) * 32 + k0];
#pragma unroll
      for (int kk = 0; kk < 4; ++kk) {
        float4 w0 = *(const float4*)&W_s[cur][(k0 + kk) * 128 + 4 * tc];
        float4 w1 = *(const float4*)&W_s[cur][(k0 + kk) * 128 + 64 + 4 * tc];
#pragma unroll
        for (int i = 0; i < 8; ++i) {
          float a = (kk == 0) ? a4[i].x : (kk == 1) ? a4[i].y
                  : (kk == 2) ? a4[i].z : a4[i].w;
          acc[i][0] += a * w0.x; acc[i][1] += a * w0.y;
          acc[i][2] += a * w0.z; acc[i][3] += a * w0.w;
          acc[i][4] += a * w1.x; acc[i][5] += a * w1.y;
          acc[i][6] += a * w1.z; acc[i][7] += a * w1.w;
        }
      }
    }
    __syncthreads();   // vmcnt(0) here: staged loads had the k-loop to land
  }

#pragma unroll
  for (int i = 0; i < 8; ++i) {
    int n = nodeBase + tr * 8 + i;
    if (n < N_NODES) {
      float* o = hout + (size_t)n * FDIM;
      float4 v0, v1;
      v0.x = fmaxf(acc[i][0], 0.f); v0.y = fmaxf(acc[i][1], 0.f);
      v0.z = fmaxf(acc[i][2], 0.f); v0.w = fmaxf(acc[i][3], 0.f);
      v1.x = fmaxf(acc[i][4], 0.f); v1.y = fmaxf(acc[i][5], 0.f);
      v1.z = fmaxf(acc[i][6], 0.f); v1.w = fmaxf(acc[i][7], 0.f);
      *(float4*)(o + 4 * tc) = v0;
      *(float4*)(o + 64 + 4 * tc) = v1;
      if (hbf) {
        unsigned short* ob = hbf + (size_t)n * FDIM;
        uint2 p0, p1;
        p0.x = bfr(v0.x) | (bfr(v0.y) << 16);
        p0.y = bfr(v0.z) | (bfr(v0.w) << 16);
        p1.x = bfr(v1.x) | (bfr(v1.y) << 16);
        p1.y = bfr(v1.z) | (bfr(v1.w) << 16);
        *(uint2*)(ob + 4 * tc) = p0;
        *(uint2*)(ob + 64 + 4 * tc) = p1;
      }
    }
  }
}

// ---------------- per-graph segment boundaries (batch is sorted) ------------
__global__ void find_starts_kernel(const int* __restrict__ batch,
                                   int* __restrict__ start) {
  int i = blockIdx.x * 256 + threadIdx.x;
  if (i >= N_NODES) return;
  int b  = batch[i];
  int bp = (i == 0) ? -1 : batch[i - 1];
  for (int g = bp + 1; g <= b; ++g) start[g] = i;
  if (i == N_NODES - 1) {
    for (int g = b + 1; g <= N_GRAPHS; ++g) start[g] = N_NODES;
  }
}

// ---------------- pooling: max & sum per graph ----------------
__global__ __launch_bounds__(128) void pool_kernel(
    const float* __restrict__ h2, const int* __restrict__ start,
    float* __restrict__ pool) {
  int g = blockIdx.x >> 3;
  int c = blockIdx.x & 7;
  int f = threadIdx.x;
  int s = start[g], e = start[g + 1];
  int len = e - s;
  int lo = s + (int)(((long long)len * c) >> 3);
  int hi = s + (int)(((long long)len * (c + 1)) >> 3);
  float mx = 0.f, sm = 0.f;
  for (int n = lo; n < hi; ++n) {
    float v = h2[(size_t)n * FDIM + f];
    mx = fmaxf(mx, v);
    sm += v;
  }
  atomicMax((unsigned int*)&pool[g * 256 + f], __float_as_uint(mx));
  atomicAdd(&pool[g * 256 + 128 + f], sm);
}

__global__ void pool_fin_kernel(float* __restrict__ pool,
                                const int* __restrict__ start) {
  int gid = blockIdx.x * 256 + threadIdx.x;   // 8192
  int g = gid >> 7, f = gid & 127;
  int cnt = start[g + 1] - start[g];
  float c = (float)(cnt > 1 ? cnt : 1);
  pool[g * 256 + 128 + f] /= c;
}

// ---------------- MLP head ----------------
__global__ void head1_kernel(const float* __restrict__ pool,
                             const float* __restrict__ lw1,
                             const float* __restrict__ lb1,
                             float* __restrict__ t1) {
  int gid = blockIdx.x * 256 + threadIdx.x;   // 8192
  int r = gid >> 7, c = gid & 127;
  float acc = lb1[c];
  for (int k = 0; k < 256; ++k) acc += pool[r * 256 + k] * lw1[k * 128 + c];
  t1[gid] = fmaxf(acc, 0.f);
}

__global__ void head2_kernel(const float* __restrict__ t1,
                             const float* __restrict__ lw2,
                             const float* __restrict__ lb2,
                             float* __restrict__ t2) {
  int gid = blockIdx.x * 256 + threadIdx.x;   // 4096
  int r = gid >> 6, c = gid & 63;
  float acc = lb2[c];
  for (int k = 0; k < 128; ++k) acc += t1[r * 128 + k] * lw2[k * 64 + c];
  t2[gid] = fmaxf(acc, 0.f);
}

__global__ __launch_bounds__(256) void head3_kernel(
    const float* __restrict__ t2, const float* __restrict__ lw3,
    const float* __restrict__ lb3, float* __restrict__ out) {
  __shared__ float lg[N_GRAPHS * N_LABELS];
  __shared__ float col[N_LABELS];
  int tid = threadIdx.x;
  for (int o = tid; o < N_GRAPHS * N_LABELS; o += 256) {
    int r = o / N_LABELS, c = o - r * N_LABELS;
    float acc = lb3[c];
    for (int k = 0; k < 64; ++k) acc += t2[r * 64 + k] * lw3[k * N_LABELS + c];
    lg[o] = acc;
  }
  __syncthreads();
  if (tid < N_LABELS) {
    float m = -1e30f;
    for (int r = 0; r < N_GRAPHS; ++r) m = fmaxf(m, lg[r * N_LABELS + tid]);
    float s = 0.f;
    for (int r = 0; r < N_GRAPHS; ++r) s += expf(lg[r * N_LABELS + tid] - m);
    col[tid] = m + logf(s);
  }
  __syncthreads();
  for (int o = tid; o < N_GRAPHS * N_LABELS; o += 256) {
    int c = o % N_LABELS;
    out[o] = lg[o] - col[c];
  }
}

// ---------------- launch ----------------
extern "C" void kernel_launch(void* const* d_in, const int* in_sizes, int n_in,
                              void* d_out, int out_size, void* d_ws, size_t ws_size,
                              hipStream_t stream) {
  const int*   x     = (const int*)  d_in[0];
  const int*   ei    = (const int*)  d_in[1];
  const int*   batch = (const int*)  d_in[2];
  const float* emb   = (const float*)d_in[3];
  const float* w1rel = (const float*)d_in[4];
  const float* w1rt  = (const float*)d_in[5];
  const float* b1    = (const float*)d_in[6];
  const float* w2rel = (const float*)d_in[7];
  const float* w2rt  = (const float*)d_in[8];
  const float* b2    = (const float*)d_in[9];
  const float* lw1   = (const float*)d_in[10];
  const float* lb1   = (const float*)d_in[11];
  const float* lw2   = (const float*)d_in[12];
  const float* lb2   = (const float*)d_in[13];
  const float* lw3   = (const float*)d_in[14];
  const float* lb3   = (const float*)d_in[15];
  float* out = (float*)d_out;

  char* ws = (char*)d_ws;
  const size_t HB   = 51200000;    // N_NODES*FDIM*4
  const size_t CSRB = 6400128;     // (N_EDGES+8) ints
  const size_t OFFB = 400128;      // (N_NODES+1) ints, rounded
  float* hB      = (float*)(ws);
  // emb_bf aliases hB[0:12.8M]: dead before gemm1 writes hB
  unsigned short* embbf = (unsigned short*)(ws);
  float* aggbuf  = (float*)(ws + HB);
  // ebuf aliases aggbuf: dead before agg1 writes aggbuf
  int*   ebuf    = (int*)  (ws + HB);
  int*   csr     = (int*)  (ws + 2 * HB);
  // cntmat/S/bsum alias csr: dead before fill2 writes csr
  int*   cntmat  = (int*)  (ws + 2 * HB);
  int*   S       = (int*)  (ws + 2 * HB + 400128);
  int*   bsum    = (int*)  (ws + 2 * HB + 800256);
  int*   csr2    = (int*)  (ws + 2 * HB + CSRB);
  int*   offsets = (int*)  (ws + 2 * HB + 2 * CSRB);
  int*   bstart  = (int*)  (ws + 2 * HB + 2 * CSRB + OFFB);            // 6,400
  float* zrow    = (float*)(ws + 2 * HB + 2 * CSRB + OFFB + 6400);     // 512
  int*   start   = (int*)  (ws + 2 * HB + 2 * CSRB + OFFB + 6912);     // 512
  float* pool    = (float*)(ws + 2 * HB + 2 * CSRB + OFFB + 7424);     // 65,536
  float* t1      = (float*)(ws + 2 * HB + 2 * CSRB + OFFB + 72960);    // 32,768
  float* t2      = (float*)(ws + 2 * HB + 2 * CSRB + OFFB + 105728);   // 16,384
  unsigned short* hbf =
      (unsigned short*)(ws + 2 * HB + 2 * CSRB + OFFB + 122112);       // 25.6 MB

  init_kernel<<<64, 256, 0, stream>>>(pool, zrow, csr, csr2, offsets);

  cvt_emb_kernel<<<6250, 256, 0, stream>>>(emb, embbf);

  histA_kernel<<<NCHUNKS, 256, 0, stream>>>(ei, cntmat);
  scanB1_kernel<<<SB_BLOCKS, 256, 0, stream>>>(cntmat, S, bsum);
  scanB2_kernel<<<1, 512, 0, stream>>>(bsum);
  scanB3_kernel<<<SB_BLOCKS, 256, 0, stream>>>(S, bsum, bstart);
  scatA_kernel<<<NCHUNKS, 256, 0, stream>>>(ei, S, ebuf);
  fill2_kernel<<<P_BKT, 256, 0, stream>>>(ebuf, bstart, x, offsets, csr, csr2);

  // layer 1: aggregate bf16 emb rows via csr2 = x[src]; h-term via x (fp32)
  agg_kernel<true><<<N_NODES / 8, 256, 0, stream>>>(embbf, csr2, offsets, zrow,
                                                    aggbuf);
  gemm_kernel<<<(N_NODES + 127) / 128, 256, 0, stream>>>(
      aggbuf, emb, x, w1rel, w1rt, b1, hB, hbf);

  // layer 2: aggregate bf16 h1 rows via csr; in-place gemm on hB (fp32)
  agg_kernel<true><<<N_NODES / 8, 256, 0, stream>>>(hbf, csr, offsets, zrow,
                                                    aggbuf);
  gemm_kernel<<<(N_NODES + 127) / 128, 256, 0, stream>>>(
      aggbuf, hB, (const int*)nullptr, w2rel, w2rt, b2, hB,
      (unsigned short*)nullptr);

  find_starts_kernel<<<SB_BLOCKS, 256, 0, stream>>>(batch, start);
  pool_kernel<<<N_GRAPHS * 8, 128, 0, stream>>>(hB, start, pool);
  pool_fin_kernel<<<32, 256, 0, stream>>>(pool, start);

  head1_kernel<<<32, 256, 0, stream>>>(pool, lw1, lb1, t1);
  head2_kernel<<<16, 256, 0, stream>>>(t1, lw2, lb2, t2);
  head3_kernel<<<1, 256, 0, stream>>>(t2, lw3, lb3, out);
}

// Round 14
// 499.171 us; speedup vs baseline: 1.5547x; 1.3088x over previous
//
#include <hip/hip_runtime.h>
#include <hip/hip_bf16.h>

#define N_NODES   100000
#define N_EDGES   1600000
#define N_GRAPHS  64
#define FDIM      128
#define N_LABELS  20
#define NBK       64                  // nodes per dst-bucket
#define P_BKT     1563                // ceil(N_NODES/NBK)
#define NCHUNKS   64                  // edge chunks
#define CHUNK     25000               // N_EDGES / NCHUNKS
#define SCAN_M    (P_BKT * NCHUNKS)   // 100032
#define SB_BLOCKS 391                 // ceil(SCAN_M/256); also covers N_NODES
#define APITCH    40                  // bf16 LDS pitch: 80 B, 16B-aligned, 2-way max

typedef __bf16 bf16x8 __attribute__((ext_vector_type(8)));
typedef float  f32x4  __attribute__((ext_vector_type(4)));
union frag_u { uint4 u; bf16x8 b; };

__device__ __forceinline__ unsigned bfr(float v) {   // fp32 -> bf16 (RTNE-ish)
  unsigned b = __float_as_uint(v);
  return (b + 0x7fffu + ((b >> 16) & 1u)) >> 16;
}

// ---------------- init: zero pool/zrow, csr pads, offsets[N] ----------------
__global__ __launch_bounds__(256) void init_kernel(
    float* __restrict__ pool, float* __restrict__ zrow,
    int* __restrict__ csr, int* __restrict__ csr2, int* __restrict__ offsets) {
  int i = blockIdx.x * 256 + threadIdx.x;
  if (i < N_GRAPHS * 256) pool[i] = 0.f;
  if (i < FDIM) zrow[i] = 0.f;
  if (i < 8) { csr[N_EDGES + i] = 0; csr2[N_EDGES + i] = 0; }
  if (i == 8) offsets[N_NODES] = N_EDGES;
}

// ---------------- emb -> bf16 (12.8 MB) ----------------
__global__ __launch_bounds__(256) void cvt_emb_kernel(
    const float* __restrict__ emb, unsigned short* __restrict__ embbf) {
  int i = blockIdx.x * 256 + threadIdx.x;   // quad id, 1,600,000 total
  float4 v = ((const float4*)emb)[i];
  uint2 o;
  o.x = bfr(v.x) | (bfr(v.y) << 16);
  o.y = bfr(v.z) | (bfr(v.w) << 16);
  ((uint2*)embbf)[i] = o;
}

// ---------------- W -> bf16, transposed: wt[c][k] = W[k][c], k in [0,256) ----
// W = [wrel (k<128); wroot (k>=128)] per layer. 2 layers x 32768 elements.
__global__ __launch_bounds__(256) void cvt_w_kernel(
    const float* __restrict__ w1rel, const float* __restrict__ w1rt,
    const float* __restrict__ w2rel, const float* __restrict__ w2rt,
    unsigned short* __restrict__ wt1, unsigned short* __restrict__ wt2) {
  int gid = blockIdx.x * 256 + threadIdx.x;   // 65536
  int l = gid >> 15;
  int rem = gid & 32767;
  int c = rem >> 8, k = rem & 255;
  const float* w = l ? ((k < 128) ? w2rel : w2rt) : ((k < 128) ? w1rel : w1rt);
  float v = w[(size_t)(k & 127) * FDIM + c];
  (l ? wt2 : wt1)[c * 256 + k] = (unsigned short)bfr(v);
}

// ---------------- A1: per-chunk bucket histogram ----------------
__global__ __launch_bounds__(256) void histA_kernel(
    const int* __restrict__ ei, int* __restrict__ cntmat) {
  __shared__ int hist[P_BKT];
  int tid = threadIdx.x;
  for (int i = tid; i < P_BKT; i += 256) hist[i] = 0;
  __syncthreads();
  int base = blockIdx.x * CHUNK;
  for (int i = tid; i < CHUNK; i += 256) {
    int d = ei[N_EDGES + base + i];
    atomicAdd(&hist[d >> 6], 1);
  }
  __syncthreads();
  for (int p = tid; p < P_BKT; p += 256)
    cntmat[p * NCHUNKS + blockIdx.x] = hist[p];
}

// ---------------- A2: 3-level exclusive scan over cntmat (bucket-major) -----
__global__ __launch_bounds__(256) void scanB1_kernel(
    const int* __restrict__ v, int* __restrict__ part,
    int* __restrict__ bsum) {
  __shared__ int s[256];
  int tid = threadIdx.x;
  int i = blockIdx.x * 256 + tid;
  int val = (i < SCAN_M) ? v[i] : 0;
  s[tid] = val;
  __syncthreads();
  for (int off = 1; off < 256; off <<= 1) {
    int t = (tid >= off) ? s[tid - off] : 0;
    __syncthreads();
    s[tid] += t;
    __syncthreads();
  }
  if (i < SCAN_M) part[i] = s[tid] - val;
  if (tid == 255) bsum[blockIdx.x] = s[255];
}

__global__ __launch_bounds__(512) void scanB2_kernel(int* __restrict__ bsum) {
  __shared__ int s[512];
  int tid = threadIdx.x;
  int v = (tid < SB_BLOCKS) ? bsum[tid] : 0;
  s[tid] = v;
  __syncthreads();
  for (int off = 1; off < 512; off <<= 1) {
    int t = (tid >= off) ? s[tid - off] : 0;
    __syncthreads();
    s[tid] += t;
    __syncthreads();
  }
  if (tid < SB_BLOCKS) bsum[tid] = s[tid] - v;
}

__global__ __launch_bounds__(256) void scanB3_kernel(
    int* __restrict__ part, const int* __restrict__ bsum,
    int* __restrict__ bstart) {
  int i = blockIdx.x * 256 + threadIdx.x;
  if (i < SCAN_M) {
    int o = part[i] + bsum[blockIdx.x];
    part[i] = o;
    if ((i & (NCHUNKS - 1)) == 0) bstart[i >> 6] = o;
  }
  if (blockIdx.x == 0 && threadIdx.x == 0) bstart[P_BKT] = N_EDGES;
}

// ---------------- A3: scatter edges grouped by bucket (packed src<<6|ldst) --
__global__ __launch_bounds__(256) void scatA_kernel(
    const int* __restrict__ ei, const int* __restrict__ S,
    int* __restrict__ ebuf) {
  __shared__ int rc[P_BKT];
  int tid = threadIdx.x;
  for (int p = tid; p < P_BKT; p += 256)
    rc[p] = S[p * NCHUNKS + blockIdx.x];
  __syncthreads();
  int base = blockIdx.x * CHUNK;
  for (int i = tid; i < CHUNK; i += 256) {
    int s0 = ei[base + i];
    int d0 = ei[N_EDGES + base + i];
    int pos = atomicAdd(&rc[d0 >> 6], 1);
    ebuf[pos] = (s0 << 6) | (d0 & 63);
  }
}

// ---------------- A4: per-bucket CSR build (single-writer csr window) -------
__global__ __launch_bounds__(256) void fill2_kernel(
    const int* __restrict__ ebuf, const int* __restrict__ bstart,
    const int* __restrict__ x, int* __restrict__ offsets,
    int* __restrict__ csr, int* __restrict__ csr2) {
  __shared__ int ldeg[NBK], loffs[NBK], rc2[NBK];
  int tid = threadIdx.x;
  int p = blockIdx.x;
  int beg = bstart[p], end = bstart[p + 1];
  if (tid < NBK) ldeg[tid] = 0;
  __syncthreads();
  for (int i = beg + tid; i < end; i += 256)
    atomicAdd(&ldeg[ebuf[i] & 63], 1);
  __syncthreads();
  if (tid == 0) {
    int run = 0;
    for (int r = 0; r < NBK; ++r) { loffs[r] = run; run += ldeg[r]; }
  }
  __syncthreads();
  if (tid < NBK) {
    rc2[tid] = loffs[tid];
    int gn = p * NBK + tid;
    if (gn < N_NODES) offsets[gn] = beg + loffs[tid];
  }
  __syncthreads();
  for (int i = beg + tid; i < end; i += 256) {
    int e = ebuf[i];
    int ld = e & 63;
    int src = e >> 6;
    int pos = atomicAdd(&rc2[ld], 1);
    csr[beg + pos] = src;
    csr2[beg + pos] = x[src];
  }
}

// ---------------- aggregation: aggout(bf16) = sum feat(bf16 rows) ------------
__global__ __launch_bounds__(256) void agg_kernel(
    const unsigned short* __restrict__ feat, const int* __restrict__ srcidx,
    const int* __restrict__ offs, const float* __restrict__ zrow,
    unsigned short* __restrict__ aggout) {
  int sub = threadIdx.x >> 5;
  int fq  = threadIdx.x & 31;
  int node = blockIdx.x * 8 + sub;

  float4 acc0 = make_float4(0.f, 0.f, 0.f, 0.f);
  float4 acc1 = make_float4(0.f, 0.f, 0.f, 0.f);
  int s = offs[node], e = offs[node + 1];

  const uint2* __restrict__ fb = (const uint2*)feat;
  const uint2* __restrict__ zb = (const uint2*)zrow;  // 256 B of zero bits
  for (int p = s; p < e; p += 8) {
    const uint2* rp[8];
#pragma unroll
    for (int u = 0; u < 8; ++u) {
      int iu = srcidx[p + u];                       // safe: padded by 8
      rp[u] = (p + u < e) ? (fb + (size_t)iu * 32) : zb;
    }
    uint2 w[8];
#pragma unroll
    for (int u = 0; u < 8; ++u) w[u] = rp[u][fq];
#pragma unroll
    for (int u = 0; u < 8; ++u) {
      float4& A = (u & 1) ? acc1 : acc0;
      A.x += __uint_as_float(w[u].x << 16);
      A.y += __uint_as_float(w[u].x & 0xffff0000u);
      A.z += __uint_as_float(w[u].y << 16);
      A.w += __uint_as_float(w[u].y & 0xffff0000u);
    }
  }
  float4 a = make_float4(acc0.x + acc1.x, acc0.y + acc1.y,
                         acc0.z + acc1.z, acc0.w + acc1.w);
  uint2 o;
  o.x = bfr(a.x) | (bfr(a.y) << 16);
  o.y = bfr(a.z) | (bfr(a.w) << 16);
  ((uint2*)aggout)[(size_t)node * 32 + fq] = o;
}

// ---------------- GEMM (bf16 MFMA): out = relu([agg|root]@[Wt^T] + b) -------
// Block 128 rows x 128 cols, 4 waves; wave w: rows [32w,32w+32) x 128 cols.
// mfma_f32_16x16x32_bf16; frag maps (m89/m120): A[m=lane&15][k=(lane>>4)*8+j],
// B[k][n=lane&15], C/D col=lane&15 row=(lane>>4)*4+reg.
// A_s rows [128][APITCH] bf16; B_s = Wt slab [128 cols][APITCH].
__global__ __launch_bounds__(256) void gemm_kernel(
    const unsigned short* __restrict__ aggbf,
    const unsigned short* __restrict__ rootbf,
    const int* __restrict__ hidx,
    const unsigned short* __restrict__ wt,      // [128 c][256 k] bf16
    const float* __restrict__ bias,
    float* __restrict__ hout_f32,               // layer-2 output
    unsigned short* __restrict__ hout_bf) {     // layer-1 output
  __shared__ unsigned short A_s[128 * APITCH];
  __shared__ unsigned short B_s[128 * APITCH];
  int tid = threadIdx.x;
  int nodeBase = blockIdx.x * 128;
  int lane = tid & 63;
  int wv = tid >> 6;
  int wbase = wv * 32;
  int lo = lane & 15, hi = lane >> 4;

  // staging: slot i covers chunk f = tid + 256*i (0..511): row=f>>2, part=f&3
  const unsigned short* a_src[2];
  const unsigned short* r_src[2];
  int s_dst[2], w_off[2];
#pragma unroll
  for (int i = 0; i < 2; ++i) {
    int f = tid + 256 * i;
    int row = f >> 2, part = f & 3;
    int gn = nodeBase + row;
    if (gn > N_NODES - 1) gn = N_NODES - 1;
    int hr = hidx ? hidx[gn] : gn;
    a_src[i] = aggbf + (size_t)gn * FDIM + part * 8;
    r_src[i] = rootbf + (size_t)hr * FDIM + part * 8;
    s_dst[i] = row * APITCH + part * 8;
    w_off[i] = row * 256 + part * 8;      // col=row
  }

  f32x4 acc[2][8];
#pragma unroll
  for (int nt = 0; nt < 8; ++nt) {
    float b = bias[nt * 16 + lo];
#pragma unroll
    for (int mt = 0; mt < 2; ++mt) {
      acc[mt][nt][0] = b; acc[mt][nt][1] = b;
      acc[mt][nt][2] = b; acc[mt][nt][3] = b;
    }
  }

#pragma unroll 1
  for (int t = 0; t < 8; ++t) {
    __syncthreads();
#pragma unroll
    for (int i = 0; i < 2; ++i) {
      const unsigned short* sa = (t < 4) ? (a_src[i] + t * 32)
                                         : (r_src[i] + (t - 4) * 32);
      *(uint4*)&A_s[s_dst[i]] = *(const uint4*)sa;
      *(uint4*)&B_s[s_dst[i]] = *(const uint4*)(wt + w_off[i] + t * 32);
    }
    __syncthreads();

    frag_u af[2], bfv[8];
#pragma unroll
    for (int mt = 0; mt < 2; ++mt)
      af[mt].u = *(const uint4*)&A_s[(wbase + mt * 16 + lo) * APITCH + hi * 8];
#pragma unroll
    for (int nt = 0; nt < 8; ++nt)
      bfv[nt].u = *(const uint4*)&B_s[(nt * 16 + lo) * APITCH + hi * 8];
#pragma unroll
    for (int mt = 0; mt < 2; ++mt)
#pragma unroll
      for (int nt = 0; nt < 8; ++nt)
        acc[mt][nt] = __builtin_amdgcn_mfma_f32_16x16x32_bf16(
            af[mt].b, bfv[nt].b, acc[mt][nt], 0, 0, 0);
  }

  // epilogue: C/D row = hi*4 + r, col = nt*16 + lo
#pragma unroll
  for (int mt = 0; mt < 2; ++mt) {
#pragma unroll
    for (int r = 0; r < 4; ++r) {
      int n = nodeBase + wbase + mt * 16 + hi * 4 + r;
      if (n < N_NODES) {
        if (hout_bf) {
          unsigned short* o = hout_bf + (size_t)n * FDIM + lo;
#pragma unroll
          for (int nt = 0; nt < 8; ++nt)
            o[nt * 16] = (unsigned short)bfr(fmaxf(acc[mt][nt][r], 0.f));
        } else {
          float* o = hout_f32 + (size_t)n * FDIM + lo;
#pragma unroll
          for (int nt = 0; nt < 8; ++nt)
            o[nt * 16] = fmaxf(acc[mt][nt][r], 0.f);
        }
      }
    }
  }
}

// ---------------- per-graph segment boundaries (batch is sorted) ------------
__global__ void find_starts_kernel(const int* __restrict__ batch,
                                   int* __restrict__ start) {
  int i = blockIdx.x * 256 + threadIdx.x;
  if (i >= N_NODES) return;
  int b  = batch[i];
  int bp = (i == 0) ? -1 : batch[i - 1];
  for (int g = bp + 1; g <= b; ++g) start[g] = i;
  if (i == N_NODES - 1) {
    for (int g = b + 1; g <= N_GRAPHS; ++g) start[g] = N_NODES;
  }
}

// ---------------- pooling: max & sum per graph ----------------
__global__ __launch_bounds__(128) void pool_kernel(
    const float* __restrict__ h2, const int* __restrict__ start,
    float* __restrict__ pool) {
  int g = blockIdx.x >> 3;
  int c = blockIdx.x & 7;
  int f = threadIdx.x;
  int s = start[g], e = start[g + 1];
  int len = e - s;
  int lo = s + (int)(((long long)len * c) >> 3);
  int hi = s + (int)(((long long)len * (c + 1)) >> 3);
  float mx = 0.f, sm = 0.f;
  for (int n = lo; n < hi; ++n) {
    float v = h2[(size_t)n * FDIM + f];
    mx = fmaxf(mx, v);
    sm += v;
  }
  atomicMax((unsigned int*)&pool[g * 256 + f], __float_as_uint(mx));
  atomicAdd(&pool[g * 256 + 128 + f], sm);
}

__global__ void pool_fin_kernel(float* __restrict__ pool,
                                const int* __restrict__ start) {
  int gid = blockIdx.x * 256 + threadIdx.x;   // 8192
  int g = gid >> 7, f = gid & 127;
  int cnt = start[g + 1] - start[g];
  float c = (float)(cnt > 1 ? cnt : 1);
  pool[g * 256 + 128 + f] /= c;
}

// ---------------- MLP head ----------------
__global__ void head1_kernel(const float* __restrict__ pool,
                             const float* __restrict__ lw1,
                             const float* __restrict__ lb1,
                             float* __restrict__ t1) {
  int gid = blockIdx.x * 256 + threadIdx.x;   // 8192
  int r = gid >> 7, c = gid & 127;
  float acc = lb1[c];
  for (int k = 0; k < 256; ++k) acc += pool[r * 256 + k] * lw1[k * 128 + c];
  t1[gid] = fmaxf(acc, 0.f);
}

__global__ void head2_kernel(const float* __restrict__ t1,
                             const float* __restrict__ lw2,
                             const float* __restrict__ lb2,
                             float* __restrict__ t2) {
  int gid = blockIdx.x * 256 + threadIdx.x;   // 4096
  int r = gid >> 6, c = gid & 63;
  float acc = lb2[c];
  for (int k = 0; k < 128; ++k) acc += t1[r * 128 + k] * lw2[k * 64 + c];
  t2[gid] = fmaxf(acc, 0.f);
}

__global__ __launch_bounds__(256) void head3_kernel(
    const float* __restrict__ t2, const float* __restrict__ lw3,
    const float* __restrict__ lb3, float* __restrict__ out) {
  __shared__ float lg[N_GRAPHS * N_LABELS];
  __shared__ float col[N_LABELS];
  int tid = threadIdx.x;
  for (int o = tid; o < N_GRAPHS * N_LABELS; o += 256) {
    int r = o / N_LABELS, c = o - r * N_LABELS;
    float acc = lb3[c];
    for (int k = 0; k < 64; ++k) acc += t2[r * 64 + k] * lw3[k * N_LABELS + c];
    lg[o] = acc;
  }
  __syncthreads();
  if (tid < N_LABELS) {
    float m = -1e30f;
    for (int r = 0; r < N_GRAPHS; ++r) m = fmaxf(m, lg[r * N_LABELS + tid]);
    float s = 0.f;
    for (int r = 0; r < N_GRAPHS; ++r) s += expf(lg[r * N_LABELS + tid] - m);
    col[tid] = m + logf(s);
  }
  __syncthreads();
  for (int o = tid; o < N_GRAPHS * N_LABELS; o += 256) {
    int c = o % N_LABELS;
    out[o] = lg[o] - col[c];
  }
}

// ---------------- launch ----------------
extern "C" void kernel_launch(void* const* d_in, const int* in_sizes, int n_in,
                              void* d_out, int out_size, void* d_ws, size_t ws_size,
                              hipStream_t stream) {
  const int*   x     = (const int*)  d_in[0];
  const int*   ei    = (const int*)  d_in[1];
  const int*   batch = (const int*)  d_in[2];
  const float* emb   = (const float*)d_in[3];
  const float* w1rel = (const float*)d_in[4];
  const float* w1rt  = (const float*)d_in[5];
  const float* b1    = (const float*)d_in[6];
  const float* w2rel = (const float*)d_in[7];
  const float* w2rt  = (const float*)d_in[8];
  const float* b2    = (const float*)d_in[9];
  const float* lw1   = (const float*)d_in[10];
  const float* lb1   = (const float*)d_in[11];
  const float* lw2   = (const float*)d_in[12];
  const float* lb2   = (const float*)d_in[13];
  const float* lw3   = (const float*)d_in[14];
  const float* lb3   = (const float*)d_in[15];
  float* out = (float*)d_out;

  char* ws = (char*)d_ws;
  const size_t HB   = 51200000;    // N_NODES*FDIM*4
  const size_t CSRB = 6400128;     // (N_EDGES+8) ints
  const size_t OFFB = 400128;      // (N_NODES+1) ints, rounded
  float* hB      = (float*)(ws);
  // embbf aliases hB: dead before gemm2 writes hB
  unsigned short* embbf = (unsigned short*)(ws);
  // aggbf (25.6 MB used of HB) aliases ebuf region
  unsigned short* aggbf = (unsigned short*)(ws + HB);
  int*   ebuf    = (int*)  (ws + HB);
  int*   csr     = (int*)  (ws + 2 * HB);
  // cntmat/S/bsum alias csr: dead before fill2 writes csr
  int*   cntmat  = (int*)  (ws + 2 * HB);
  int*   S       = (int*)  (ws + 2 * HB + 400128);
  int*   bsum    = (int*)  (ws + 2 * HB + 800256);
  int*   csr2    = (int*)  (ws + 2 * HB + CSRB);
  int*   offsets = (int*)  (ws + 2 * HB + 2 * CSRB);
  int*   bstart  = (int*)  (ws + 2 * HB + 2 * CSRB + OFFB);            // 6,400
  float* zrow    = (float*)(ws + 2 * HB + 2 * CSRB + OFFB + 6400);     // 512
  int*   start   = (int*)  (ws + 2 * HB + 2 * CSRB + OFFB + 6912);     // 512
  float* pool    = (float*)(ws + 2 * HB + 2 * CSRB + OFFB + 7424);     // 65,536
  float* t1      = (float*)(ws + 2 * HB + 2 * CSRB + OFFB + 72960);    // 32,768
  float* t2      = (float*)(ws + 2 * HB + 2 * CSRB + OFFB + 105728);   // 16,384
  unsigned short* hbf =
      (unsigned short*)(ws + 2 * HB + 2 * CSRB + OFFB + 122112);       // 25.6 MB
  unsigned short* wt1 =
      (unsigned short*)(ws + 2 * HB + 2 * CSRB + OFFB + 122112 + 25600000);
  unsigned short* wt2 = wt1 + 128 * 256;

  init_kernel<<<64, 256, 0, stream>>>(pool, zrow, csr, csr2, offsets);

  cvt_emb_kernel<<<6250, 256, 0, stream>>>(emb, embbf);
  cvt_w_kernel<<<256, 256, 0, stream>>>(w1rel, w1rt, w2rel, w2rt, wt1, wt2);

  histA_kernel<<<NCHUNKS, 256, 0, stream>>>(ei, cntmat);
  scanB1_kernel<<<SB_BLOCKS, 256, 0, stream>>>(cntmat, S, bsum);
  scanB2_kernel<<<1, 512, 0, stream>>>(bsum);
  scanB3_kernel<<<SB_BLOCKS, 256, 0, stream>>>(S, bsum, bstart);
  scatA_kernel<<<NCHUNKS, 256, 0, stream>>>(ei, S, ebuf);
  fill2_kernel<<<P_BKT, 256, 0, stream>>>(ebuf, bstart, x, offsets, csr, csr2);

  // layer 1: agg over bf16 emb rows (csr2 = x[src]); root = embbf via x
  agg_kernel<<<N_NODES / 8, 256, 0, stream>>>(embbf, csr2, offsets, zrow, aggbf);
  gemm_kernel<<<(N_NODES + 127) / 128, 256, 0, stream>>>(
      aggbf, embbf, x, wt1, b1, (float*)nullptr, hbf);

  // layer 2: agg over bf16 h1 rows (csr); root = hbf; fp32 out for pooling
  agg_kernel<<<N_NODES / 8, 256, 0, stream>>>(hbf, csr, offsets, zrow, aggbf);
  gemm_kernel<<<(N_NODES + 127) / 128, 256, 0, stream>>>(
      aggbf, hbf, (const int*)nullptr, wt2, b2, hB,
      (unsigned short*)nullptr);

  find_starts_kernel<<<SB_BLOCKS, 256, 0, stream>>>(batch, start);
  pool_kernel<<<N_GRAPHS * 8, 128, 0, stream>>>(hB, start, pool);
  pool_fin_kernel<<<32, 256, 0, stream>>>(pool, start);

  head1_kernel<<<32, 256, 0, stream>>>(pool, lw1, lb1, t1);
  head2_kernel<<<16, 256, 0, stream>>>(t1, lw2, lb2, t2);
  head3_kernel<<<1, 256, 0, stream>>>(t2, lw3, lb3, out);
}